// Round 8
// baseline (221.641 us; speedup 1.0000x reference)
//
#include <hip/hip_runtime.h>
#include <cstddef>
#include <cstdint>

#define NB 4
#define S_LEN 2048
#define DK 1024

typedef __attribute__((ext_vector_type(8))) short short8;       // 8 bf16 = 4 VGPR (MFMA A/B frag)
typedef __attribute__((ext_vector_type(4))) float floatx4;      // MFMA C/D frag
typedef __attribute__((ext_vector_type(4))) unsigned short ushort4v;
typedef __attribute__((ext_vector_type(8))) unsigned short ushort8v;

__device__ inline unsigned short f2bf(float f) {
    unsigned int u = __float_as_uint(f);
    u += 0x7fff + ((u >> 16) & 1);   // round-to-nearest-even
    return (unsigned short)(u >> 16);
}
__device__ inline float bf2f(unsigned short u) {
    return __uint_as_float(((unsigned int)u) << 16);
}

#define GLD16(gp, lp)                                                                  \
    __builtin_amdgcn_global_load_lds(                                                  \
        (const __attribute__((address_space(1))) unsigned int*)(gp),                   \
        (__attribute__((address_space(3))) unsigned int*)(lp), 16, 0, 0)

// Stage a 128x64 bf16 tile into LDS with XOR swizzle: LDS[row][pg] holds
// global colgroup (pg ^ (row&7)).  Fragment reads use pg = cg ^ (row&7).
__device__ inline void stage128x64(const unsigned short* __restrict__ g, size_t ld,
                                   unsigned short* __restrict__ lds,
                                   int w, int lane)
{
    const int r8 = lane >> 3;
    const int cg = (lane & 7) ^ r8;
    const unsigned short* gp = g + (size_t)(w * 8 + r8) * ld + cg * 8;
    unsigned short* lp = lds + (size_t)(w * 8) * 64;
    #pragma unroll
    for (int seg = 0; seg < 4; ++seg)
        GLD16(gp + (size_t)(seg * 32) * ld, lp + (size_t)seg * 32 * 64);
}

// Same, 64 rows.
__device__ inline void stage64x64(const unsigned short* __restrict__ g, size_t ld,
                                  unsigned short* __restrict__ lds,
                                  int w, int lane)
{
    const int r8 = lane >> 3;
    const int cg = (lane & 7) ^ r8;
    const unsigned short* gp = g + (size_t)(w * 8 + r8) * ld + cg * 8;
    unsigned short* lp = lds + (size_t)(w * 8) * 64;
    #pragma unroll
    for (int seg = 0; seg < 2; ++seg)
        GLD16(gp + (size_t)(seg * 32) * ld, lp + (size_t)seg * 32 * 64);
}

// ---------------------------------------------------------------------------
// K0: cast fp32 -> bf16 for x, Wq, Wk, Wv
// ---------------------------------------------------------------------------
__global__ __launch_bounds__(256) void cast_all(
    const float* __restrict__ x, const float* __restrict__ Wq,
    const float* __restrict__ Wk, const float* __restrict__ Wv,
    unsigned short* __restrict__ xb, unsigned short* __restrict__ wqb,
    unsigned short* __restrict__ wkb, unsigned short* __restrict__ wvb)
{
    const float* src; unsigned short* dst; int n4;
    if (blockIdx.z == 0)      { src = x;  dst = xb;  n4 = (int)((size_t)NB * S_LEN * DK / 4); }
    else if (blockIdx.z == 1) { src = Wq; dst = wqb; n4 = DK * DK / 4; }
    else if (blockIdx.z == 2) { src = Wk; dst = wkb; n4 = DK * DK / 4; }
    else                      { src = Wv; dst = wvb; n4 = DK * DK / 4; }
    const int stride = gridDim.x * 256;
    for (int i = blockIdx.x * 256 + threadIdx.x; i < n4; i += stride) {
        float4 f = ((const float4*)src)[i];
        ushort4v o;
        o.x = f2bf(f.x); o.y = f2bf(f.y); o.z = f2bf(f.z); o.w = f2bf(f.w);
        ((ushort4v*)dst)[i] = o;
    }
}

// ---------------------------------------------------------------------------
// K1: fused QKV projection, bf16 MFMA, 128x128 tile, BK=64, swizzled LDS.
// z==2 (v) writes TRANSPOSED vT[b][o][s].
// COMPUTE-SKIP for z<2 on all-invalid m-tiles; epilogue always writes.
// ---------------------------------------------------------------------------
__global__ __launch_bounds__(256) void qkv_mfma(
    const unsigned short* __restrict__ xb,
    const unsigned short* __restrict__ wqb, const unsigned short* __restrict__ wkb,
    const unsigned short* __restrict__ wvb,
    const float* __restrict__ bq, const float* __restrict__ bk, const float* __restrict__ bv,
    const int* __restrict__ lengths,
    unsigned short* __restrict__ qb, unsigned short* __restrict__ kb,
    unsigned short* __restrict__ vTb)
{
    __shared__ unsigned short As[128 * 64];
    __shared__ unsigned short Bs[128 * 64];
    const int tid  = threadIdx.x;
    const int w    = tid >> 6, lane = tid & 63;
    const int lm   = lane & 15, quad = lane >> 4;
    const int xr   = lm & 7;
    const int m0   = blockIdx.x * 128, n0 = blockIdx.y * 128;
    const int z    = blockIdx.z;
    const unsigned short* Wb = (z == 0) ? wqb : (z == 1) ? wkb : wvb;
    const float* bias        = (z == 0) ? bq  : (z == 1) ? bk  : bv;

    const int bidx = m0 >> 11;
    const int len  = lengths[bidx];
    const int sm0  = m0 & (S_LEN - 1);
    const bool do_compute = (z == 2) || (sm0 < len);

    const unsigned short* Ag = xb + (size_t)m0 * DK;
    const unsigned short* Bg = Wb + (size_t)n0 * DK;

    const int wr = (w >> 1) * 64, wc = (w & 1) * 64;

    floatx4 acc[4][4];
    #pragma unroll
    for (int r = 0; r < 4; ++r)
        #pragma unroll
        for (int c = 0; c < 4; ++c) acc[r][c] = (floatx4)0.0f;

    if (do_compute) {
        for (int k0 = 0; k0 < DK; k0 += 64) {
            stage128x64(Ag + k0, DK, As, w, lane);
            stage128x64(Bg + k0, DK, Bs, w, lane);
            __syncthreads();
            #pragma unroll
            for (int ks = 0; ks < 2; ++ks) {
                short8 af[4], bf[4];
                #pragma unroll
                for (int r = 0; r < 4; ++r)
                    af[r] = *(const short8*)&As[(size_t)(wr + r*16 + lm) * 64 + ((((ks<<2)|quad) ^ xr) << 3)];
                #pragma unroll
                for (int c = 0; c < 4; ++c)
                    bf[c] = *(const short8*)&Bs[(size_t)(wc + c*16 + lm) * 64 + ((((ks<<2)|quad) ^ xr) << 3)];
                #pragma unroll
                for (int r = 0; r < 4; ++r)
                    #pragma unroll
                    for (int c = 0; c < 4; ++c)
                        acc[r][c] = __builtin_amdgcn_mfma_f32_16x16x32_bf16(af[r], bf[c], acc[r][c], 0, 0, 0);
            }
            __syncthreads();
        }
    }

    if (z < 2) {
        unsigned short* out = (z == 0) ? qb : kb;
        #pragma unroll
        for (int r = 0; r < 4; ++r) {
            const int gm = m0 + wr + r * 16 + quad * 4;
            #pragma unroll
            for (int c = 0; c < 4; ++c) {
                const int gn = n0 + wc + c * 16 + lm;
                const float bb = bias[gn];
                #pragma unroll
                for (int e = 0; e < 4; ++e)
                    out[(size_t)(gm + e) * DK + gn] = f2bf(acc[r][c][e] + bb);
            }
        }
    } else {
        #pragma unroll
        for (int r = 0; r < 4; ++r) {
            const int gm = m0 + wr + r * 16 + quad * 4;
            const int sm = gm & (S_LEN - 1);
            #pragma unroll
            for (int c = 0; c < 4; ++c) {
                const int gn = n0 + wc + c * 16 + lm;
                const float bb = bias[gn];
                ushort4v pk;
                pk.x = f2bf(acc[r][c][0] + bb);
                pk.y = f2bf(acc[r][c][1] + bb);
                pk.z = f2bf(acc[r][c][2] + bb);
                pk.w = f2bf(acc[r][c][3] + bb);
                *(ushort4v*)&vTb[((size_t)bidx * DK + gn) * S_LEN + sm] = pk;
            }
        }
    }
}

// ---------------------------------------------------------------------------
// K2: scores -> unnormalized probabilities u (bf16) + per-tile row sums
// tsum[b][i][bj] (fp32).  Compact triangular grid; COMPUTE-SKIP for
// constant tiles (epilogue bytes identical).  tsum written for EVERY
// lower-triangle tile -> pv's reads (bj<=bi) are always covered.
// ---------------------------------------------------------------------------
__global__ __launch_bounds__(256) void score_mfma(
    const unsigned short* __restrict__ qb, const unsigned short* __restrict__ kb,
    unsigned short* __restrict__ ub, float* __restrict__ tsum,
    const int* __restrict__ lengths)
{
    const int t = blockIdx.x, b = blockIdx.y;
    int bi = (int)((sqrtf(8.0f * t + 1.0f) - 1.0f) * 0.5f);
    while ((bi + 1) * (bi + 2) / 2 <= t) ++bi;
    while (bi * (bi + 1) / 2 > t) --bi;
    const int bj = t - bi * (bi + 1) / 2;
    const int m0 = bi * 128, n0 = bj * 128;
    const int len = lengths[b];

    __shared__ unsigned short As[128 * 64];
    __shared__ unsigned short Bs[128 * 64];
    __shared__ float psum[128][2];
    const int tid  = threadIdx.x;
    const int w    = tid >> 6, lane = tid & 63;
    const int lm   = lane & 15, quad = lane >> 4;
    const int xr   = lm & 7;
    const unsigned short* Ag = qb + (size_t)b * S_LEN * DK + (size_t)m0 * DK;
    const unsigned short* Bg = kb + (size_t)b * S_LEN * DK + (size_t)n0 * DK;
    unsigned short* Ub = ub + (size_t)b * S_LEN * S_LEN;

    const int wr = (w >> 1) * 64, wc = (w & 1) * 64;

    floatx4 acc[4][4];
    #pragma unroll
    for (int r = 0; r < 4; ++r)
        #pragma unroll
        for (int c = 0; c < 4; ++c) acc[r][c] = (floatx4)0.0f;

    if (m0 < len && n0 < len) {
        for (int k0 = 0; k0 < DK; k0 += 64) {
            stage128x64(Ag + k0, DK, As, w, lane);
            stage128x64(Bg + k0, DK, Bs, w, lane);
            __syncthreads();
            #pragma unroll
            for (int ks = 0; ks < 2; ++ks) {
                short8 af[4], bf[4];
                #pragma unroll
                for (int r = 0; r < 4; ++r)
                    af[r] = *(const short8*)&As[(size_t)(wr + r*16 + lm) * 64 + ((((ks<<2)|quad) ^ xr) << 3)];
                #pragma unroll
                for (int c = 0; c < 4; ++c)
                    bf[c] = *(const short8*)&Bs[(size_t)(wc + c*16 + lm) * 64 + ((((ks<<2)|quad) ^ xr) << 3)];
                #pragma unroll
                for (int r = 0; r < 4; ++r)
                    #pragma unroll
                    for (int c = 0; c < 4; ++c)
                        acc[r][c] = __builtin_amdgcn_mfma_f32_16x16x32_bf16(af[r], bf[c], acc[r][c], 0, 0, 0);
            }
            __syncthreads();
        }
    }
    __syncthreads();   // protect psum (re-used LDS phase)

    float part[4][4];  // row-partial sums over this lane's 4 cols
    #pragma unroll
    for (int r = 0; r < 4; ++r)
        #pragma unroll
        for (int e = 0; e < 4; ++e) part[r][e] = 0.0f;

    #pragma unroll
    for (int r = 0; r < 4; ++r) {
        const int gm = m0 + wr + r * 16 + quad * 4;
        #pragma unroll
        for (int c = 0; c < 4; ++c) {
            const int gn = n0 + wc + c * 16 + lm;
            #pragma unroll
            for (int e = 0; e < 4; ++e) {
                const int i = gm + e;
                float u;
                if (gn > i)          u = 0.0f;
                else if (i >= len)   u = 1.0f;
                else                 u = __expf(acc[r][c][e] * 0.03125f);
                const unsigned short ub16 = f2bf(u);
                Ub[(size_t)i * S_LEN + gn] = ub16;
                part[r][e] += bf2f(ub16);      // sum what pv will consume
            }
        }
    }

    // reduce over the 16 col-lanes (lm bits 0..3; stays within the quad)
    #pragma unroll
    for (int r = 0; r < 4; ++r)
        #pragma unroll
        for (int e = 0; e < 4; ++e) {
            part[r][e] += __shfl_xor(part[r][e], 1, 64);
            part[r][e] += __shfl_xor(part[r][e], 2, 64);
            part[r][e] += __shfl_xor(part[r][e], 4, 64);
            part[r][e] += __shfl_xor(part[r][e], 8, 64);
        }
    if (lm == 0) {
        #pragma unroll
        for (int r = 0; r < 4; ++r)
            #pragma unroll
            for (int e = 0; e < 4; ++e)
                psum[wr + r * 16 + quad * 4 + e][w & 1] = part[r][e];
    }
    __syncthreads();
    if (tid < 128)
        tsum[((size_t)b * S_LEN + m0 + tid) * 16 + bj] = psum[tid][0] + psum[tid][1];
}

// ---------------------------------------------------------------------------
// K3: O[b][i][o] = (1/l_i) * sum_j u[b][i][j] vT[b][o][j], bf16 MFMA.
// 128x64 tiles (16 n-chunks) -> critical-path block costs half per iter;
// descending-bi block order so any non-resident leftovers are short blocks.
// l_i = sum of tsum partials over bj<=bi (deterministic, computed in
// prologue; K-loop is pure MFMA+staging).
// ---------------------------------------------------------------------------
__global__ __launch_bounds__(256) void pv_mfma(
    const unsigned short* __restrict__ ub, const unsigned short* __restrict__ vTb,
    const float* __restrict__ tsum, float* __restrict__ out)
{
    __shared__ unsigned short As[128 * 64];
    __shared__ unsigned short Bs[64 * 64];
    __shared__ float inv_lds[128];
    const int tid  = threadIdx.x;
    const int w    = tid >> 6, lane = tid & 63;
    const int lm   = lane & 15, quad = lane >> 4;
    const int xr   = lm & 7;
    const int bi = 15 - blockIdx.x;            // descending work order
    const int bn = blockIdx.y, b = blockIdx.z;
    const int m0 = bi * 128, n0 = bn * 64;
    const unsigned short* Ag = ub  + (size_t)b * S_LEN * S_LEN + (size_t)m0 * S_LEN;
    const unsigned short* Bg = vTb + (size_t)b * DK * S_LEN    + (size_t)n0 * S_LEN;

    // prologue: per-row normalizers from tile sums
    if (tid < 128) {
        const float* ts = &tsum[((size_t)b * S_LEN + m0 + tid) * 16];
        float s = 0.0f;
        for (int j = 0; j <= bi; ++j) s += ts[j];
        inv_lds[tid] = 1.0f / s;
    }

    const int wr = (w >> 1) * 64, wc = (w & 1) * 32;
    const int kend = (bi + 1) * 128;

    floatx4 acc[4][2];
    #pragma unroll
    for (int r = 0; r < 4; ++r)
        #pragma unroll
        for (int c = 0; c < 2; ++c) acc[r][c] = (floatx4)0.0f;

    for (int k0 = 0; k0 < kend; k0 += 64) {
        stage128x64(Ag + k0, S_LEN, As, w, lane);
        stage64x64 (Bg + k0, S_LEN, Bs, w, lane);
        __syncthreads();
        #pragma unroll
        for (int ks = 0; ks < 2; ++ks) {
            short8 af[4], bf[2];
            #pragma unroll
            for (int r = 0; r < 4; ++r)
                af[r] = *(const short8*)&As[(size_t)(wr + r*16 + lm) * 64 + ((((ks<<2)|quad) ^ xr) << 3)];
            #pragma unroll
            for (int c = 0; c < 2; ++c)
                bf[c] = *(const short8*)&Bs[(size_t)(wc + c*16 + lm) * 64 + ((((ks<<2)|quad) ^ xr) << 3)];
            #pragma unroll
            for (int r = 0; r < 4; ++r)
                #pragma unroll
                for (int c = 0; c < 2; ++c)
                    acc[r][c] = __builtin_amdgcn_mfma_f32_16x16x32_bf16(af[r], bf[c], acc[r][c], 0, 0, 0);
        }
        __syncthreads();
    }

    #pragma unroll
    for (int r = 0; r < 4; ++r) {
        const int lrow = wr + r * 16 + quad * 4;
        const int gm = m0 + lrow;
        float ilv[4];
        #pragma unroll
        for (int e = 0; e < 4; ++e) ilv[e] = inv_lds[lrow + e];
        #pragma unroll
        for (int c = 0; c < 2; ++c) {
            const int gn = n0 + wc + c * 16 + lm;
            #pragma unroll
            for (int e = 0; e < 4; ++e)
                out[((size_t)b * S_LEN + gm + e) * DK + gn] = acc[r][c][e] * ilv[e];
        }
    }
}

// ---------------------------------------------------------------------------
extern "C" void kernel_launch(void* const* d_in, const int* in_sizes, int n_in,
                              void* d_out, int out_size, void* d_ws, size_t ws_size,
                              hipStream_t stream)
{
    const float* x  = (const float*)d_in[0];
    const float* Wq = (const float*)d_in[1];
    const float* bq = (const float*)d_in[2];
    const float* Wk = (const float*)d_in[3];
    const float* bk = (const float*)d_in[4];
    const float* Wv = (const float*)d_in[5];
    const float* bv = (const float*)d_in[6];
    const int* lengths = (const int*)d_in[7];
    float* out = (float*)d_out;

    // workspace (bf16 elements): qb | kb | vTb | xb | Wqb | Wkb | Wvb | ub | tsum
    const size_t NQ = (size_t)NB * S_LEN * DK;       // 8388608
    const size_t NW = (size_t)DK * DK;               // 1048576
    const size_t NP = (size_t)NB * S_LEN * S_LEN;    // 16777216
    unsigned short* ws16 = (unsigned short*)d_ws;
    unsigned short* qb  = ws16;
    unsigned short* kb_ = ws16 + NQ;
    unsigned short* vTb = ws16 + 2 * NQ;
    unsigned short* xb  = ws16 + 3 * NQ;
    unsigned short* wqb = ws16 + 4 * NQ;
    unsigned short* wkb = wqb + NW;
    unsigned short* wvb = wkb + NW;
    unsigned short* ub  = ws16 + 4 * NQ + 3 * NW;    // bf16 unnormalized probs
    float* tsum = (float*)(ub + NP);                 // [NB][S_LEN][16] fp32

    cast_all<<<dim3(1024, 1, 4), 256, 0, stream>>>(x, Wq, Wk, Wv, xb, wqb, wkb, wvb);
    qkv_mfma<<<dim3(64, 8, 3), 256, 0, stream>>>(xb, wqb, wkb, wvb, bq, bk, bv, lengths,
                                                 qb, kb_, vTb);
    score_mfma<<<dim3(136, NB), 256, 0, stream>>>(qb, kb_, ub, tsum, lengths);
    pv_mfma<<<dim3(16, 16, NB), 256, 0, stream>>>(ub, vTb, tsum, out);
}

// Round 9
// 219.536 us; speedup vs baseline: 1.0096x; 1.0096x over previous
//
#include <hip/hip_runtime.h>
#include <cstddef>
#include <cstdint>

#define NB 4
#define S_LEN 2048
#define DK 1024

typedef __attribute__((ext_vector_type(8))) short short8;       // 8 bf16 = 4 VGPR (MFMA A/B frag)
typedef __attribute__((ext_vector_type(4))) float floatx4;      // MFMA C/D frag
typedef __attribute__((ext_vector_type(4))) unsigned short ushort4v;
typedef __attribute__((ext_vector_type(8))) unsigned short ushort8v;

__device__ inline unsigned short f2bf(float f) {
    unsigned int u = __float_as_uint(f);
    u += 0x7fff + ((u >> 16) & 1);   // round-to-nearest-even
    return (unsigned short)(u >> 16);
}
__device__ inline float bf2f(unsigned short u) {
    return __uint_as_float(((unsigned int)u) << 16);
}

#define GLD16(gp, lp)                                                                  \
    __builtin_amdgcn_global_load_lds(                                                  \
        (const __attribute__((address_space(1))) unsigned int*)(gp),                   \
        (__attribute__((address_space(3))) unsigned int*)(lp), 16, 0, 0)

// Stage a 128x64 bf16 tile into LDS with XOR swizzle: LDS[row][pg] holds
// global colgroup (pg ^ (row&7)).  Fragment reads use pg = cg ^ (row&7).
__device__ inline void stage128x64(const unsigned short* __restrict__ g, size_t ld,
                                   unsigned short* __restrict__ lds,
                                   int w, int lane)
{
    const int r8 = lane >> 3;
    const int cg = (lane & 7) ^ r8;
    const unsigned short* gp = g + (size_t)(w * 8 + r8) * ld + cg * 8;
    unsigned short* lp = lds + (size_t)(w * 8) * 64;
    #pragma unroll
    for (int seg = 0; seg < 4; ++seg)
        GLD16(gp + (size_t)(seg * 32) * ld, lp + (size_t)seg * 32 * 64);
}

// ---------------------------------------------------------------------------
// K0: cast fp32 -> bf16 for x, Wq, Wk, Wv
// ---------------------------------------------------------------------------
__global__ __launch_bounds__(256) void cast_all(
    const float* __restrict__ x, const float* __restrict__ Wq,
    const float* __restrict__ Wk, const float* __restrict__ Wv,
    unsigned short* __restrict__ xb, unsigned short* __restrict__ wqb,
    unsigned short* __restrict__ wkb, unsigned short* __restrict__ wvb)
{
    const float* src; unsigned short* dst; int n4;
    if (blockIdx.z == 0)      { src = x;  dst = xb;  n4 = (int)((size_t)NB * S_LEN * DK / 4); }
    else if (blockIdx.z == 1) { src = Wq; dst = wqb; n4 = DK * DK / 4; }
    else if (blockIdx.z == 2) { src = Wk; dst = wkb; n4 = DK * DK / 4; }
    else                      { src = Wv; dst = wvb; n4 = DK * DK / 4; }
    const int stride = gridDim.x * 256;
    for (int i = blockIdx.x * 256 + threadIdx.x; i < n4; i += stride) {
        float4 f = ((const float4*)src)[i];
        ushort4v o;
        o.x = f2bf(f.x); o.y = f2bf(f.y); o.z = f2bf(f.z); o.w = f2bf(f.w);
        ((ushort4v*)dst)[i] = o;
    }
}

// ---------------------------------------------------------------------------
// K1: fused QKV projection, bf16 MFMA, 128x128 tile, BK=64, swizzled LDS.
// z==2 (v) writes TRANSPOSED vT[b][o][s].
// COMPUTE-SKIP for z<2 on all-invalid m-tiles; epilogue always writes.
// ---------------------------------------------------------------------------
__global__ __launch_bounds__(256) void qkv_mfma(
    const unsigned short* __restrict__ xb,
    const unsigned short* __restrict__ wqb, const unsigned short* __restrict__ wkb,
    const unsigned short* __restrict__ wvb,
    const float* __restrict__ bq, const float* __restrict__ bk, const float* __restrict__ bv,
    const int* __restrict__ lengths,
    unsigned short* __restrict__ qb, unsigned short* __restrict__ kb,
    unsigned short* __restrict__ vTb)
{
    __shared__ unsigned short As[128 * 64];
    __shared__ unsigned short Bs[128 * 64];
    const int tid  = threadIdx.x;
    const int w    = tid >> 6, lane = tid & 63;
    const int lm   = lane & 15, quad = lane >> 4;
    const int xr   = lm & 7;
    const int m0   = blockIdx.x * 128, n0 = blockIdx.y * 128;
    const int z    = blockIdx.z;
    const unsigned short* Wb = (z == 0) ? wqb : (z == 1) ? wkb : wvb;
    const float* bias        = (z == 0) ? bq  : (z == 1) ? bk  : bv;

    const int bidx = m0 >> 11;
    const int len  = lengths[bidx];
    const int sm0  = m0 & (S_LEN - 1);
    const bool do_compute = (z == 2) || (sm0 < len);

    const unsigned short* Ag = xb + (size_t)m0 * DK;
    const unsigned short* Bg = Wb + (size_t)n0 * DK;

    const int wr = (w >> 1) * 64, wc = (w & 1) * 64;

    floatx4 acc[4][4];
    #pragma unroll
    for (int r = 0; r < 4; ++r)
        #pragma unroll
        for (int c = 0; c < 4; ++c) acc[r][c] = (floatx4)0.0f;

    if (do_compute) {
        for (int k0 = 0; k0 < DK; k0 += 64) {
            stage128x64(Ag + k0, DK, As, w, lane);
            stage128x64(Bg + k0, DK, Bs, w, lane);
            __syncthreads();
            #pragma unroll
            for (int ks = 0; ks < 2; ++ks) {
                short8 af[4], bf[4];
                #pragma unroll
                for (int r = 0; r < 4; ++r)
                    af[r] = *(const short8*)&As[(size_t)(wr + r*16 + lm) * 64 + ((((ks<<2)|quad) ^ xr) << 3)];
                #pragma unroll
                for (int c = 0; c < 4; ++c)
                    bf[c] = *(const short8*)&Bs[(size_t)(wc + c*16 + lm) * 64 + ((((ks<<2)|quad) ^ xr) << 3)];
                #pragma unroll
                for (int r = 0; r < 4; ++r)
                    #pragma unroll
                    for (int c = 0; c < 4; ++c)
                        acc[r][c] = __builtin_amdgcn_mfma_f32_16x16x32_bf16(af[r], bf[c], acc[r][c], 0, 0, 0);
            }
            __syncthreads();
        }
    }

    if (z < 2) {
        unsigned short* out = (z == 0) ? qb : kb;
        #pragma unroll
        for (int r = 0; r < 4; ++r) {
            const int gm = m0 + wr + r * 16 + quad * 4;
            #pragma unroll
            for (int c = 0; c < 4; ++c) {
                const int gn = n0 + wc + c * 16 + lm;
                const float bb = bias[gn];
                #pragma unroll
                for (int e = 0; e < 4; ++e)
                    out[(size_t)(gm + e) * DK + gn] = f2bf(acc[r][c][e] + bb);
            }
        }
    } else {
        #pragma unroll
        for (int r = 0; r < 4; ++r) {
            const int gm = m0 + wr + r * 16 + quad * 4;
            const int sm = gm & (S_LEN - 1);
            #pragma unroll
            for (int c = 0; c < 4; ++c) {
                const int gn = n0 + wc + c * 16 + lm;
                const float bb = bias[gn];
                ushort4v pk;
                pk.x = f2bf(acc[r][c][0] + bb);
                pk.y = f2bf(acc[r][c][1] + bb);
                pk.z = f2bf(acc[r][c][2] + bb);
                pk.w = f2bf(acc[r][c][3] + bb);
                *(ushort4v*)&vTb[((size_t)bidx * DK + gn) * S_LEN + sm] = pk;
            }
        }
    }
}

// ---------------------------------------------------------------------------
// K2: scores -> unnormalized probabilities u (bf16) + per-tile row sums
// tsum[b][i][bj] (fp32).  Compact triangular grid; COMPUTE-SKIP for
// constant tiles (epilogue bytes identical).  tsum written for EVERY
// lower-triangle tile -> pv's reads (bj<=bi) are always covered.
// ---------------------------------------------------------------------------
__global__ __launch_bounds__(256) void score_mfma(
    const unsigned short* __restrict__ qb, const unsigned short* __restrict__ kb,
    unsigned short* __restrict__ ub, float* __restrict__ tsum,
    const int* __restrict__ lengths)
{
    const int t = blockIdx.x, b = blockIdx.y;
    int bi = (int)((sqrtf(8.0f * t + 1.0f) - 1.0f) * 0.5f);
    while ((bi + 1) * (bi + 2) / 2 <= t) ++bi;
    while (bi * (bi + 1) / 2 > t) --bi;
    const int bj = t - bi * (bi + 1) / 2;
    const int m0 = bi * 128, n0 = bj * 128;
    const int len = lengths[b];

    __shared__ unsigned short As[128 * 64];
    __shared__ unsigned short Bs[128 * 64];
    __shared__ float psum[128][2];
    const int tid  = threadIdx.x;
    const int w    = tid >> 6, lane = tid & 63;
    const int lm   = lane & 15, quad = lane >> 4;
    const int xr   = lm & 7;
    const unsigned short* Ag = qb + (size_t)b * S_LEN * DK + (size_t)m0 * DK;
    const unsigned short* Bg = kb + (size_t)b * S_LEN * DK + (size_t)n0 * DK;
    unsigned short* Ub = ub + (size_t)b * S_LEN * S_LEN;

    const int wr = (w >> 1) * 64, wc = (w & 1) * 64;

    floatx4 acc[4][4];
    #pragma unroll
    for (int r = 0; r < 4; ++r)
        #pragma unroll
        for (int c = 0; c < 4; ++c) acc[r][c] = (floatx4)0.0f;

    if (m0 < len && n0 < len) {
        for (int k0 = 0; k0 < DK; k0 += 64) {
            stage128x64(Ag + k0, DK, As, w, lane);
            stage128x64(Bg + k0, DK, Bs, w, lane);
            __syncthreads();
            #pragma unroll
            for (int ks = 0; ks < 2; ++ks) {
                short8 af[4], bf[4];
                #pragma unroll
                for (int r = 0; r < 4; ++r)
                    af[r] = *(const short8*)&As[(size_t)(wr + r*16 + lm) * 64 + ((((ks<<2)|quad) ^ xr) << 3)];
                #pragma unroll
                for (int c = 0; c < 4; ++c)
                    bf[c] = *(const short8*)&Bs[(size_t)(wc + c*16 + lm) * 64 + ((((ks<<2)|quad) ^ xr) << 3)];
                #pragma unroll
                for (int r = 0; r < 4; ++r)
                    #pragma unroll
                    for (int c = 0; c < 4; ++c)
                        acc[r][c] = __builtin_amdgcn_mfma_f32_16x16x32_bf16(af[r], bf[c], acc[r][c], 0, 0, 0);
            }
            __syncthreads();
        }
    }
    __syncthreads();   // protect psum (re-used LDS phase)

    float part[4][4];  // row-partial sums over this lane's 4 cols
    #pragma unroll
    for (int r = 0; r < 4; ++r)
        #pragma unroll
        for (int e = 0; e < 4; ++e) part[r][e] = 0.0f;

    #pragma unroll
    for (int r = 0; r < 4; ++r) {
        const int gm = m0 + wr + r * 16 + quad * 4;
        #pragma unroll
        for (int c = 0; c < 4; ++c) {
            const int gn = n0 + wc + c * 16 + lm;
            #pragma unroll
            for (int e = 0; e < 4; ++e) {
                const int i = gm + e;
                float u;
                if (gn > i)          u = 0.0f;
                else if (i >= len)   u = 1.0f;
                else                 u = __expf(acc[r][c][e] * 0.03125f);
                const unsigned short ub16 = f2bf(u);
                Ub[(size_t)i * S_LEN + gn] = ub16;
                part[r][e] += bf2f(ub16);      // sum what pv will consume
            }
        }
    }

    // reduce over the 16 col-lanes (lm bits 0..3; stays within the quad)
    #pragma unroll
    for (int r = 0; r < 4; ++r)
        #pragma unroll
        for (int e = 0; e < 4; ++e) {
            part[r][e] += __shfl_xor(part[r][e], 1, 64);
            part[r][e] += __shfl_xor(part[r][e], 2, 64);
            part[r][e] += __shfl_xor(part[r][e], 4, 64);
            part[r][e] += __shfl_xor(part[r][e], 8, 64);
        }
    if (lm == 0) {
        #pragma unroll
        for (int r = 0; r < 4; ++r)
            #pragma unroll
            for (int e = 0; e < 4; ++e)
                psum[wr + r * 16 + quad * 4 + e][w & 1] = part[r][e];
    }
    __syncthreads();
    if (tid < 128)
        tsum[((size_t)b * S_LEN + m0 + tid) * 16 + bj] = psum[tid][0] + psum[tid][1];
}

// ---------------------------------------------------------------------------
// K3: O[b][i][o] = (1/l_i) * sum_j u[b][i][j] vT[b][o][j], bf16 MFMA.
// 128x128 tiles.  COMPLEMENTARY-BI SWIZZLE: bi = (b&2) ? 15-x : x, so the
// co-resident block pair (c, c+256) — which the XCD round-robin puts on the
// same CU and which differ only in batch bit 1 — carries bi and 15-bi:
// every CU gets a uniform 34 K-iters instead of up to 64.  (Heuristic only;
// any other mapping is merely round-7 behavior.)
// l_i = sum of tsum partials over bj<=bi (prologue; K-loop is pure MFMA).
// ---------------------------------------------------------------------------
__global__ __launch_bounds__(256) void pv_mfma(
    const unsigned short* __restrict__ ub, const unsigned short* __restrict__ vTb,
    const float* __restrict__ tsum, float* __restrict__ out)
{
    __shared__ unsigned short As[128 * 64];
    __shared__ unsigned short Bs[128 * 64];
    __shared__ float inv_lds[128];
    const int tid  = threadIdx.x;
    const int w    = tid >> 6, lane = tid & 63;
    const int lm   = lane & 15, quad = lane >> 4;
    const int xr   = lm & 7;
    const int b  = blockIdx.z, bn = blockIdx.y;
    const int bi = (b & 2) ? (15 - blockIdx.x) : blockIdx.x;   // complementary pairing
    const int m0 = bi * 128, n0 = bn * 128;
    const unsigned short* Ag = ub  + (size_t)b * S_LEN * S_LEN + (size_t)m0 * S_LEN;
    const unsigned short* Bg = vTb + (size_t)b * DK * S_LEN    + (size_t)n0 * S_LEN;

    // prologue: per-row normalizers from tile sums (K-loop barriers order
    // this write before the epilogue's reads)
    if (tid < 128) {
        const float* ts = &tsum[((size_t)b * S_LEN + m0 + tid) * 16];
        float s = 0.0f;
        for (int j = 0; j <= bi; ++j) s += ts[j];
        inv_lds[tid] = 1.0f / s;
    }

    const int wr = (w >> 1) * 64, wc = (w & 1) * 64;
    const int kend = (bi + 1) * 128;

    floatx4 acc[4][4];
    #pragma unroll
    for (int r = 0; r < 4; ++r)
        #pragma unroll
        for (int c = 0; c < 4; ++c) acc[r][c] = (floatx4)0.0f;

    for (int k0 = 0; k0 < kend; k0 += 64) {
        stage128x64(Ag + k0, S_LEN, As, w, lane);
        stage128x64(Bg + k0, S_LEN, Bs, w, lane);
        __syncthreads();
        #pragma unroll
        for (int ks = 0; ks < 2; ++ks) {
            short8 af[4], bf[4];
            #pragma unroll
            for (int r = 0; r < 4; ++r)
                af[r] = *(const short8*)&As[(size_t)(wr + r*16 + lm) * 64 + ((((ks<<2)|quad) ^ xr) << 3)];
            #pragma unroll
            for (int c = 0; c < 4; ++c)
                bf[c] = *(const short8*)&Bs[(size_t)(wc + c*16 + lm) * 64 + ((((ks<<2)|quad) ^ xr) << 3)];
            #pragma unroll
            for (int r = 0; r < 4; ++r)
                #pragma unroll
                for (int c = 0; c < 4; ++c)
                    acc[r][c] = __builtin_amdgcn_mfma_f32_16x16x32_bf16(af[r], bf[c], acc[r][c], 0, 0, 0);
        }
        __syncthreads();
    }

    #pragma unroll
    for (int r = 0; r < 4; ++r) {
        const int lrow = wr + r * 16 + quad * 4;
        const int gm = m0 + lrow;
        float ilv[4];
        #pragma unroll
        for (int e = 0; e < 4; ++e) ilv[e] = inv_lds[lrow + e];
        #pragma unroll
        for (int c = 0; c < 4; ++c) {
            const int gn = n0 + wc + c * 16 + lm;
            #pragma unroll
            for (int e = 0; e < 4; ++e)
                out[((size_t)b * S_LEN + gm + e) * DK + gn] = acc[r][c][e] * ilv[e];
        }
    }
}

// ---------------------------------------------------------------------------
extern "C" void kernel_launch(void* const* d_in, const int* in_sizes, int n_in,
                              void* d_out, int out_size, void* d_ws, size_t ws_size,
                              hipStream_t stream)
{
    const float* x  = (const float*)d_in[0];
    const float* Wq = (const float*)d_in[1];
    const float* bq = (const float*)d_in[2];
    const float* Wk = (const float*)d_in[3];
    const float* bk = (const float*)d_in[4];
    const float* Wv = (const float*)d_in[5];
    const float* bv = (const float*)d_in[6];
    const int* lengths = (const int*)d_in[7];
    float* out = (float*)d_out;

    // workspace (bf16 elements): qb | kb | vTb | xb | Wqb | Wkb | Wvb | ub | tsum
    const size_t NQ = (size_t)NB * S_LEN * DK;       // 8388608
    const size_t NW = (size_t)DK * DK;               // 1048576
    const size_t NP = (size_t)NB * S_LEN * S_LEN;    // 16777216
    unsigned short* ws16 = (unsigned short*)d_ws;
    unsigned short* qb  = ws16;
    unsigned short* kb_ = ws16 + NQ;
    unsigned short* vTb = ws16 + 2 * NQ;
    unsigned short* xb  = ws16 + 3 * NQ;
    unsigned short* wqb = ws16 + 4 * NQ;
    unsigned short* wkb = wqb + NW;
    unsigned short* wvb = wkb + NW;
    unsigned short* ub  = ws16 + 4 * NQ + 3 * NW;    // bf16 unnormalized probs
    float* tsum = (float*)(ub + NP);                 // [NB][S_LEN][16] fp32

    cast_all<<<dim3(1024, 1, 4), 256, 0, stream>>>(x, Wq, Wk, Wv, xb, wqb, wkb, wvb);
    qkv_mfma<<<dim3(64, 8, 3), 256, 0, stream>>>(xb, wqb, wkb, wvb, bq, bk, bv, lengths,
                                                 qb, kb_, vTb);
    score_mfma<<<dim3(136, NB), 256, 0, stream>>>(qb, kb_, ub, tsum, lengths);
    pv_mfma<<<dim3(16, 8, NB), 256, 0, stream>>>(ub, vTb, tsum, out);
}

// Round 10
// 204.933 us; speedup vs baseline: 1.0815x; 1.0713x over previous
//
#include <hip/hip_runtime.h>
#include <cstddef>
#include <cstdint>

#define NB 4
#define S_LEN 2048
#define DK 1024

typedef __attribute__((ext_vector_type(8))) short short8;       // 8 bf16 = 4 VGPR (MFMA A/B frag)
typedef __attribute__((ext_vector_type(4))) float floatx4;      // MFMA C/D frag
typedef __attribute__((ext_vector_type(4))) unsigned short ushort4v;
typedef __attribute__((ext_vector_type(8))) unsigned short ushort8v;

__device__ inline unsigned short f2bf(float f) {
    unsigned int u = __float_as_uint(f);
    u += 0x7fff + ((u >> 16) & 1);   // round-to-nearest-even
    return (unsigned short)(u >> 16);
}
__device__ inline float bf2f(unsigned short u) {
    return __uint_as_float(((unsigned int)u) << 16);
}

#define GLD16(gp, lp)                                                                  \
    __builtin_amdgcn_global_load_lds(                                                  \
        (const __attribute__((address_space(1))) unsigned int*)(gp),                   \
        (__attribute__((address_space(3))) unsigned int*)(lp), 16, 0, 0)

// Stage a 128x64 bf16 tile into LDS with XOR swizzle: LDS[row][pg] holds
// global colgroup (pg ^ (row&7)).  Fragment reads use pg = cg ^ (row&7).
__device__ inline void stage128x64(const unsigned short* __restrict__ g, size_t ld,
                                   unsigned short* __restrict__ lds,
                                   int w, int lane)
{
    const int r8 = lane >> 3;
    const int cg = (lane & 7) ^ r8;
    const unsigned short* gp = g + (size_t)(w * 8 + r8) * ld + cg * 8;
    unsigned short* lp = lds + (size_t)(w * 8) * 64;
    #pragma unroll
    for (int seg = 0; seg < 4; ++seg)
        GLD16(gp + (size_t)(seg * 32) * ld, lp + (size_t)seg * 32 * 64);
}

// ---------------------------------------------------------------------------
// K0: cast fp32 -> bf16 for x, Wq, Wk, Wv
// ---------------------------------------------------------------------------
__global__ __launch_bounds__(256) void cast_all(
    const float* __restrict__ x, const float* __restrict__ Wq,
    const float* __restrict__ Wk, const float* __restrict__ Wv,
    unsigned short* __restrict__ xb, unsigned short* __restrict__ wqb,
    unsigned short* __restrict__ wkb, unsigned short* __restrict__ wvb)
{
    const float* src; unsigned short* dst; int n4;
    if (blockIdx.z == 0)      { src = x;  dst = xb;  n4 = (int)((size_t)NB * S_LEN * DK / 4); }
    else if (blockIdx.z == 1) { src = Wq; dst = wqb; n4 = DK * DK / 4; }
    else if (blockIdx.z == 2) { src = Wk; dst = wkb; n4 = DK * DK / 4; }
    else                      { src = Wv; dst = wvb; n4 = DK * DK / 4; }
    const int stride = gridDim.x * 256;
    for (int i = blockIdx.x * 256 + threadIdx.x; i < n4; i += stride) {
        float4 f = ((const float4*)src)[i];
        ushort4v o;
        o.x = f2bf(f.x); o.y = f2bf(f.y); o.z = f2bf(f.z); o.w = f2bf(f.w);
        ((ushort4v*)dst)[i] = o;
    }
}

// ---------------------------------------------------------------------------
// K1: fused QKV projection, bf16 MFMA, 128x128 tile, BK=64, swizzled LDS.
// Hardware z=0 is mapped to the v GEMM (never compute-skipped) so heavy
// blocks dispatch FIRST and length-skipped q/k blocks backfill the tail.
// z==v writes TRANSPOSED vT[b][o][s].
// COMPUTE-SKIP for q/k on all-invalid m-tiles; epilogue always writes.
// __launch_bounds__(256,3): cap regs ~170 -> 3 blocks/CU (was 2 at 172).
// ---------------------------------------------------------------------------
__global__ __launch_bounds__(256, 3) void qkv_mfma(
    const unsigned short* __restrict__ xb,
    const unsigned short* __restrict__ wqb, const unsigned short* __restrict__ wkb,
    const unsigned short* __restrict__ wvb,
    const float* __restrict__ bq, const float* __restrict__ bk, const float* __restrict__ bv,
    const int* __restrict__ lengths,
    unsigned short* __restrict__ qb, unsigned short* __restrict__ kb,
    unsigned short* __restrict__ vTb)
{
    __shared__ unsigned short As[128 * 64];
    __shared__ unsigned short Bs[128 * 64];
    const int tid  = threadIdx.x;
    const int w    = tid >> 6, lane = tid & 63;
    const int lm   = lane & 15, quad = lane >> 4;
    const int xr   = lm & 7;
    const int m0   = blockIdx.x * 128, n0 = blockIdx.y * 128;
    const int z    = (blockIdx.z == 0) ? 2 : (blockIdx.z - 1);   // hw0->v, hw1->q, hw2->k
    const unsigned short* Wb = (z == 0) ? wqb : (z == 1) ? wkb : wvb;
    const float* bias        = (z == 0) ? bq  : (z == 1) ? bk  : bv;

    const int bidx = m0 >> 11;
    const int len  = lengths[bidx];
    const int sm0  = m0 & (S_LEN - 1);
    const bool do_compute = (z == 2) || (sm0 < len);

    const unsigned short* Ag = xb + (size_t)m0 * DK;
    const unsigned short* Bg = Wb + (size_t)n0 * DK;

    const int wr = (w >> 1) * 64, wc = (w & 1) * 64;

    floatx4 acc[4][4];
    #pragma unroll
    for (int r = 0; r < 4; ++r)
        #pragma unroll
        for (int c = 0; c < 4; ++c) acc[r][c] = (floatx4)0.0f;

    if (do_compute) {
        for (int k0 = 0; k0 < DK; k0 += 64) {
            stage128x64(Ag + k0, DK, As, w, lane);
            stage128x64(Bg + k0, DK, Bs, w, lane);
            __syncthreads();
            #pragma unroll
            for (int ks = 0; ks < 2; ++ks) {
                short8 af[4], bf[4];
                #pragma unroll
                for (int r = 0; r < 4; ++r)
                    af[r] = *(const short8*)&As[(size_t)(wr + r*16 + lm) * 64 + ((((ks<<2)|quad) ^ xr) << 3)];
                #pragma unroll
                for (int c = 0; c < 4; ++c)
                    bf[c] = *(const short8*)&Bs[(size_t)(wc + c*16 + lm) * 64 + ((((ks<<2)|quad) ^ xr) << 3)];
                #pragma unroll
                for (int r = 0; r < 4; ++r)
                    #pragma unroll
                    for (int c = 0; c < 4; ++c)
                        acc[r][c] = __builtin_amdgcn_mfma_f32_16x16x32_bf16(af[r], bf[c], acc[r][c], 0, 0, 0);
            }
            __syncthreads();
        }
    }

    if (z < 2) {
        unsigned short* out = (z == 0) ? qb : kb;
        #pragma unroll
        for (int r = 0; r < 4; ++r) {
            const int gm = m0 + wr + r * 16 + quad * 4;
            #pragma unroll
            for (int c = 0; c < 4; ++c) {
                const int gn = n0 + wc + c * 16 + lm;
                const float bb = bias[gn];
                #pragma unroll
                for (int e = 0; e < 4; ++e)
                    out[(size_t)(gm + e) * DK + gn] = f2bf(acc[r][c][e] + bb);
            }
        }
    } else {
        #pragma unroll
        for (int r = 0; r < 4; ++r) {
            const int gm = m0 + wr + r * 16 + quad * 4;
            const int sm = gm & (S_LEN - 1);
            #pragma unroll
            for (int c = 0; c < 4; ++c) {
                const int gn = n0 + wc + c * 16 + lm;
                const float bb = bias[gn];
                ushort4v pk;
                pk.x = f2bf(acc[r][c][0] + bb);
                pk.y = f2bf(acc[r][c][1] + bb);
                pk.z = f2bf(acc[r][c][2] + bb);
                pk.w = f2bf(acc[r][c][3] + bb);
                *(ushort4v*)&vTb[((size_t)bidx * DK + gn) * S_LEN + sm] = pk;
            }
        }
    }
}

// ---------------------------------------------------------------------------
// K2: scores -> unnormalized probabilities u (bf16) + per-tile row sums
// tsum[b][i][bj] (fp32).  Compact triangular grid; COMPUTE-SKIP for
// constant tiles (epilogue bytes identical).  tsum written for EVERY
// lower-triangle tile -> pv's reads (bj<=bi) are always covered.
// ---------------------------------------------------------------------------
__global__ __launch_bounds__(256, 3) void score_mfma(
    const unsigned short* __restrict__ qb, const unsigned short* __restrict__ kb,
    unsigned short* __restrict__ ub, float* __restrict__ tsum,
    const int* __restrict__ lengths)
{
    const int t = blockIdx.x, b = blockIdx.y;
    int bi = (int)((sqrtf(8.0f * t + 1.0f) - 1.0f) * 0.5f);
    while ((bi + 1) * (bi + 2) / 2 <= t) ++bi;
    while (bi * (bi + 1) / 2 > t) --bi;
    const int bj = t - bi * (bi + 1) / 2;
    const int m0 = bi * 128, n0 = bj * 128;
    const int len = lengths[b];

    __shared__ unsigned short As[128 * 64];
    __shared__ unsigned short Bs[128 * 64];
    __shared__ float psum[128][2];
    const int tid  = threadIdx.x;
    const int w    = tid >> 6, lane = tid & 63;
    const int lm   = lane & 15, quad = lane >> 4;
    const int xr   = lm & 7;
    const unsigned short* Ag = qb + (size_t)b * S_LEN * DK + (size_t)m0 * DK;
    const unsigned short* Bg = kb + (size_t)b * S_LEN * DK + (size_t)n0 * DK;
    unsigned short* Ub = ub + (size_t)b * S_LEN * S_LEN;

    const int wr = (w >> 1) * 64, wc = (w & 1) * 64;

    floatx4 acc[4][4];
    #pragma unroll
    for (int r = 0; r < 4; ++r)
        #pragma unroll
        for (int c = 0; c < 4; ++c) acc[r][c] = (floatx4)0.0f;

    if (m0 < len && n0 < len) {
        for (int k0 = 0; k0 < DK; k0 += 64) {
            stage128x64(Ag + k0, DK, As, w, lane);
            stage128x64(Bg + k0, DK, Bs, w, lane);
            __syncthreads();
            #pragma unroll
            for (int ks = 0; ks < 2; ++ks) {
                short8 af[4], bf[4];
                #pragma unroll
                for (int r = 0; r < 4; ++r)
                    af[r] = *(const short8*)&As[(size_t)(wr + r*16 + lm) * 64 + ((((ks<<2)|quad) ^ xr) << 3)];
                #pragma unroll
                for (int c = 0; c < 4; ++c)
                    bf[c] = *(const short8*)&Bs[(size_t)(wc + c*16 + lm) * 64 + ((((ks<<2)|quad) ^ xr) << 3)];
                #pragma unroll
                for (int r = 0; r < 4; ++r)
                    #pragma unroll
                    for (int c = 0; c < 4; ++c)
                        acc[r][c] = __builtin_amdgcn_mfma_f32_16x16x32_bf16(af[r], bf[c], acc[r][c], 0, 0, 0);
            }
            __syncthreads();
        }
    }
    __syncthreads();   // protect psum (re-used LDS phase)

    float part[4][4];  // row-partial sums over this lane's 4 cols
    #pragma unroll
    for (int r = 0; r < 4; ++r)
        #pragma unroll
        for (int e = 0; e < 4; ++e) part[r][e] = 0.0f;

    #pragma unroll
    for (int r = 0; r < 4; ++r) {
        const int gm = m0 + wr + r * 16 + quad * 4;
        #pragma unroll
        for (int c = 0; c < 4; ++c) {
            const int gn = n0 + wc + c * 16 + lm;
            #pragma unroll
            for (int e = 0; e < 4; ++e) {
                const int i = gm + e;
                float u;
                if (gn > i)          u = 0.0f;
                else if (i >= len)   u = 1.0f;
                else                 u = __expf(acc[r][c][e] * 0.03125f);
                const unsigned short ub16 = f2bf(u);
                Ub[(size_t)i * S_LEN + gn] = ub16;
                part[r][e] += bf2f(ub16);      // sum what pv will consume
            }
        }
    }

    // reduce over the 16 col-lanes (lm bits 0..3; stays within the quad)
    #pragma unroll
    for (int r = 0; r < 4; ++r)
        #pragma unroll
        for (int e = 0; e < 4; ++e) {
            part[r][e] += __shfl_xor(part[r][e], 1, 64);
            part[r][e] += __shfl_xor(part[r][e], 2, 64);
            part[r][e] += __shfl_xor(part[r][e], 4, 64);
            part[r][e] += __shfl_xor(part[r][e], 8, 64);
        }
    if (lm == 0) {
        #pragma unroll
        for (int r = 0; r < 4; ++r)
            #pragma unroll
            for (int e = 0; e < 4; ++e)
                psum[wr + r * 16 + quad * 4 + e][w & 1] = part[r][e];
    }
    __syncthreads();
    if (tid < 128)
        tsum[((size_t)b * S_LEN + m0 + tid) * 16 + bj] = psum[tid][0] + psum[tid][1];
}

// ---------------------------------------------------------------------------
// K3: O[b][i][o] = (1/l_i) * sum_j u[b][i][j] vT[b][o][j], bf16 MFMA.
// 128x128 tiles; complementary-bi swizzle (kept, harmless).
// l_i = sum of tsum partials over bj<=bi (prologue; K-loop is pure MFMA).
// ---------------------------------------------------------------------------
__global__ __launch_bounds__(256, 3) void pv_mfma(
    const unsigned short* __restrict__ ub, const unsigned short* __restrict__ vTb,
    const float* __restrict__ tsum, float* __restrict__ out)
{
    __shared__ unsigned short As[128 * 64];
    __shared__ unsigned short Bs[128 * 64];
    __shared__ float inv_lds[128];
    const int tid  = threadIdx.x;
    const int w    = tid >> 6, lane = tid & 63;
    const int lm   = lane & 15, quad = lane >> 4;
    const int xr   = lm & 7;
    const int b  = blockIdx.z, bn = blockIdx.y;
    const int bi = (b & 2) ? (15 - blockIdx.x) : blockIdx.x;
    const int m0 = bi * 128, n0 = bn * 128;
    const unsigned short* Ag = ub  + (size_t)b * S_LEN * S_LEN + (size_t)m0 * S_LEN;
    const unsigned short* Bg = vTb + (size_t)b * DK * S_LEN    + (size_t)n0 * S_LEN;

    // prologue: per-row normalizers from tile sums (K-loop barriers order
    // this write before the epilogue's reads)
    if (tid < 128) {
        const float* ts = &tsum[((size_t)b * S_LEN + m0 + tid) * 16];
        float s = 0.0f;
        for (int j = 0; j <= bi; ++j) s += ts[j];
        inv_lds[tid] = 1.0f / s;
    }

    const int wr = (w >> 1) * 64, wc = (w & 1) * 64;
    const int kend = (bi + 1) * 128;

    floatx4 acc[4][4];
    #pragma unroll
    for (int r = 0; r < 4; ++r)
        #pragma unroll
        for (int c = 0; c < 4; ++c) acc[r][c] = (floatx4)0.0f;

    for (int k0 = 0; k0 < kend; k0 += 64) {
        stage128x64(Ag + k0, S_LEN, As, w, lane);
        stage128x64(Bg + k0, S_LEN, Bs, w, lane);
        __syncthreads();
        #pragma unroll
        for (int ks = 0; ks < 2; ++ks) {
            short8 af[4], bf[4];
            #pragma unroll
            for (int r = 0; r < 4; ++r)
                af[r] = *(const short8*)&As[(size_t)(wr + r*16 + lm) * 64 + ((((ks<<2)|quad) ^ xr) << 3)];
            #pragma unroll
            for (int c = 0; c < 4; ++c)
                bf[c] = *(const short8*)&Bs[(size_t)(wc + c*16 + lm) * 64 + ((((ks<<2)|quad) ^ xr) << 3)];
            #pragma unroll
            for (int r = 0; r < 4; ++r)
                #pragma unroll
                for (int c = 0; c < 4; ++c)
                    acc[r][c] = __builtin_amdgcn_mfma_f32_16x16x32_bf16(af[r], bf[c], acc[r][c], 0, 0, 0);
        }
        __syncthreads();
    }

    #pragma unroll
    for (int r = 0; r < 4; ++r) {
        const int lrow = wr + r * 16 + quad * 4;
        const int gm = m0 + lrow;
        float ilv[4];
        #pragma unroll
        for (int e = 0; e < 4; ++e) ilv[e] = inv_lds[lrow + e];
        #pragma unroll
        for (int c = 0; c < 4; ++c) {
            const int gn = n0 + wc + c * 16 + lm;
            #pragma unroll
            for (int e = 0; e < 4; ++e)
                out[((size_t)b * S_LEN + gm + e) * DK + gn] = acc[r][c][e] * ilv[e];
        }
    }
}

// ---------------------------------------------------------------------------
extern "C" void kernel_launch(void* const* d_in, const int* in_sizes, int n_in,
                              void* d_out, int out_size, void* d_ws, size_t ws_size,
                              hipStream_t stream)
{
    const float* x  = (const float*)d_in[0];
    const float* Wq = (const float*)d_in[1];
    const float* bq = (const float*)d_in[2];
    const float* Wk = (const float*)d_in[3];
    const float* bk = (const float*)d_in[4];
    const float* Wv = (const float*)d_in[5];
    const float* bv = (const float*)d_in[6];
    const int* lengths = (const int*)d_in[7];
    float* out = (float*)d_out;

    // workspace (bf16 elements): qb | kb | vTb | xb | Wqb | Wkb | Wvb | ub | tsum
    const size_t NQ = (size_t)NB * S_LEN * DK;       // 8388608
    const size_t NW = (size_t)DK * DK;               // 1048576
    const size_t NP = (size_t)NB * S_LEN * S_LEN;    // 16777216
    unsigned short* ws16 = (unsigned short*)d_ws;
    unsigned short* qb  = ws16;
    unsigned short* kb_ = ws16 + NQ;
    unsigned short* vTb = ws16 + 2 * NQ;
    unsigned short* xb  = ws16 + 3 * NQ;
    unsigned short* wqb = ws16 + 4 * NQ;
    unsigned short* wkb = wqb + NW;
    unsigned short* wvb = wkb + NW;
    unsigned short* ub  = ws16 + 4 * NQ + 3 * NW;    // bf16 unnormalized probs
    float* tsum = (float*)(ub + NP);                 // [NB][S_LEN][16] fp32

    cast_all<<<dim3(1024, 1, 4), 256, 0, stream>>>(x, Wq, Wk, Wv, xb, wqb, wkb, wvb);
    qkv_mfma<<<dim3(64, 8, 3), 256, 0, stream>>>(xb, wqb, wkb, wvb, bq, bk, bv, lengths,
                                                 qb, kb_, vTb);
    score_mfma<<<dim3(136, NB), 256, 0, stream>>>(qb, kb_, ub, tsum, lengths);
    pv_mfma<<<dim3(16, 8, NB), 256, 0, stream>>>(ub, vTb, tsum, out);
}